// Round 1
// baseline (22436.409 us; speedup 1.0000x reference)
//
#include <hip/hip_runtime.h>
#include <hip/hip_bf16.h>

// ---------------------------------------------------------------------------
// LSTM_66675072303478: 2-layer LSTM (B=512,S=128,E=7,H=1024) + FC(1024->672)
//
// v12 = v11 with B operands (weights) loaded DIRECTLY global->VGPR as MFMA
// fragments, bypassing LDS entirely for B. Rationale (rocprof v11): round =
// 63k cyc but MFMA floor = 15k; inner loop was LDS-throughput-bound (~147KB
// LDS reads + 40KB writes per k-iter = ~1470 cyc vs 620 cyc MFMA) with
// SQ_LDS_BANK_CONFLICT = 4.7e8. Weights are CONSTANT, so prep kernels now
// repack W0/W1/Wfc into fragment-major layout: frag(t,ks) = 1KB, lane l =
// (n&15)+((k>>3)&3)*16 holds 16 contiguous bytes -> one coalesced 1KB
// dwordx4 wave-load per fragment. 4 m-waves read identical B frags -> L1
// broadcast. A (h) stays via LDS (8KB/iter, cheap) so epilogue, h layout,
// EA-store/flag coherence scheme are all untouched. B double-buffered one
// 64-k iteration ahead (~515 cyc window).
//  - All else proven in v9/v11: weights L2-resident per XCD, EA-point h
//    stores, cached h loads + 3-slot rotation + L1-only buffer_inv, one
//    flag/round, 512 threads = 8 waves 4(m)x2(n), wave tile 16x64.
// ---------------------------------------------------------------------------

typedef __bf16 bf16x8 __attribute__((ext_vector_type(8)));
typedef float  f32x4  __attribute__((ext_vector_type(4)));

#define LDSTR 72            // LDS row stride in bf16 elems (64 data + 8 pad)
#define HSZ   (512 * 1024)  // one h buffer: 512 rows x 1024 cols (bf16)

__device__ __forceinline__ float sigm_f(float x) {
    x = fminf(30.f, fmaxf(-30.f, x));
    return 1.0f / (1.0f + __expf(-x));
}
__device__ __forceinline__ float tanh_f(float x) {
    x = fminf(30.f, fmaxf(-30.f, x));
    float e = __expf(-2.0f * x);
    return (1.0f - e) / (1.0f + e);
}

// n' = (j/16)*64 + g*16 + (j%16)  ->  original gate-major row g*1024 + j
__device__ __forceinline__ int perm_row(int np) {
    int g = (np >> 4) & 3;
    int j = ((np >> 6) << 4) | (np & 15);
    return g * 1024 + j;
}

// ---- relaxed-only flag ops (NO acquire/release -> no L2 inv/wb) ------------
__device__ __forceinline__ void spin_ge(const int* p, int target) {
    while (__hip_atomic_load(p, __ATOMIC_RELAXED, __HIP_MEMORY_SCOPE_AGENT) < target)
        __builtin_amdgcn_s_sleep(1);
}
__device__ __forceinline__ void signal_inc(int* p) {
    __hip_atomic_fetch_add(p, 1, __ATOMIC_RELAXED, __HIP_MEMORY_SCOPE_AGENT);
}
// L1-only invalidate (CU scope). Leaves L2/MALL intact; compiler fence.
__device__ __forceinline__ void inv_l1() {
    asm volatile("buffer_inv" ::: "memory");
}
// EA-point coherent dword store: bypasses L2s -> visible chip-wide.
__device__ __forceinline__ void store_ea(unsigned* p, unsigned v) {
    __hip_atomic_store(p, v, __ATOMIC_RELAXED, __HIP_MEMORY_SCOPE_AGENT);
}

// ---------------- weight prep kernels (run every call) ----------------------
// Fragment layout: for permuted gate-row np, col k:
//   tile t = np>>4, slice ks = k>>5, frag base elem = (t*NKS + ks)*512
//   lane  = (np&15) + ((k>>3)&3)*16, elem = lane*8 + (k&7)
// A wave's B-frag load is then 64 lanes x 16B contiguous = 1KB coalesced.

__global__ void prep_w0(const float* __restrict__ Wh0, __bf16* __restrict__ W0f) {
    int idx = blockIdx.x * 256 + threadIdx.x;       // 4096 np x 128 k-chunks
    int np = idx >> 7, c = idx & 127;
    int k = c << 3;
    int r = perm_row(np);
    const float* s = Wh0 + r * 1024 + k;
    float4 v0 = *(const float4*)s;
    float4 v1 = *(const float4*)(s + 4);
    int t = np >> 4, ks = k >> 5;
    int lane = (np & 15) + ((c & 3) << 4);
    __bf16* o = W0f + ((size_t)(t * 32 + ks) << 9) + (lane << 3);
    o[0] = (__bf16)v0.x; o[1] = (__bf16)v0.y; o[2] = (__bf16)v0.z; o[3] = (__bf16)v0.w;
    o[4] = (__bf16)v1.x; o[5] = (__bf16)v1.y; o[6] = (__bf16)v1.z; o[7] = (__bf16)v1.w;
}

__global__ void prep_w1(const float* __restrict__ Wi1, const float* __restrict__ Wh1,
                        __bf16* __restrict__ W1f) {
    int idx = blockIdx.x * 256 + threadIdx.x;       // 4096 np x 256 k-chunks
    int np = idx >> 8, c = idx & 255;
    int k = c << 3;
    int r = perm_row(np);
    const float* s = (k < 1024) ? (Wi1 + r * 1024 + k) : (Wh1 + r * 1024 + (k - 1024));
    float4 v0 = *(const float4*)s;
    float4 v1 = *(const float4*)(s + 4);
    int t = np >> 4, ks = k >> 5;                   // ks in [0,64)
    int lane = (np & 15) + ((c & 3) << 4);
    __bf16* o = W1f + ((size_t)(t * 64 + ks) << 9) + (lane << 3);
    o[0] = (__bf16)v0.x; o[1] = (__bf16)v0.y; o[2] = (__bf16)v0.z; o[3] = (__bf16)v0.w;
    o[4] = (__bf16)v1.x; o[5] = (__bf16)v1.y; o[6] = (__bf16)v1.z; o[7] = (__bf16)v1.w;
}

__global__ void prep_wfc(const float* __restrict__ Wfc, __bf16* __restrict__ Wfcf) {
    int idx = blockIdx.x * 256 + threadIdx.x;       // 768 n x 128 k-chunks
    int n = idx >> 7, c = idx & 127;
    int k = c << 3;
    int t = n >> 4, ks = k >> 5;
    int lane = (n & 15) + ((c & 3) << 4);
    __bf16* o = Wfcf + ((size_t)(t * 32 + ks) << 9) + (lane << 3);
    if (n < 672) {
        const float* s = Wfc + n * 1024 + k;
        float4 v0 = *(const float4*)s;
        float4 v1 = *(const float4*)(s + 4);
        o[0] = (__bf16)v0.x; o[1] = (__bf16)v0.y; o[2] = (__bf16)v0.z; o[3] = (__bf16)v0.w;
        o[4] = (__bf16)v1.x; o[5] = (__bf16)v1.y; o[6] = (__bf16)v1.z; o[7] = (__bf16)v1.w;
    } else {
        #pragma unroll
        for (int q = 0; q < 8; ++q) o[q] = (__bf16)0.f;
    }
}

__global__ void prep_small(const float* __restrict__ Wi0, const float* __restrict__ b0,
                           const float* __restrict__ b1,
                           float* __restrict__ Wi0p, float* __restrict__ b1p) {
    int np = blockIdx.x * 256 + threadIdx.x;
    int r = perm_row(np);
    float* o = Wi0p + np * 8;
    #pragma unroll
    for (int q = 0; q < 7; ++q) o[q] = Wi0[r * 7 + q];
    o[7] = b0[r];
    b1p[np] = b1[r];
}

// ---------------- fused K=1024 sub-loop, direct-fragment B ------------------
// A: staged through LDS (dbuf, 1 barrier/iter, 2-iter global prefetch) as in
// v11. B: loaded straight from the fragment-packed weight arrays into VGPRs,
// ping-pong double buffer, one 64-k iteration (16 loads) ahead of the MFMAs.
// b0f/b1f already include the (ntile + wn*4) tile base and the l*8 lane elem.
// b0f ni-stride = 32 slices, b1f ni-stride = 64 slices (K=2048).

template <bool D0, bool D1>
__device__ __forceinline__ void floopd(const __bf16* __restrict__ abase,
                                       const __bf16* __restrict__ b0f,
                                       const __bf16* __restrict__ b1f,
                                       int tid, __bf16* AldsB,
                                       f32x4 (&acc0)[4], f32x4 (&acc1)[4]) {
    const int a_r = tid >> 3;             // 0..63
    const int a_c = (tid & 7) << 3;       // 0..56 step 8 (16 B)
    const int l  = tid & 63, w = tid >> 6;
    const int wm = w & 3;
    const int lj = l & 15,  lq = l >> 4;

    const __bf16* arw = abase + a_r * 1024 + a_c;

    uint4 ra;
    bf16x8 bc0[8], bc1[8], bn0[8], bn1[8];   // cur/next, [s*4+ni]

    auto ldB = [&](int it, bf16x8 (&r0)[8], bf16x8 (&r1)[8]) {
        #pragma unroll
        for (int s = 0; s < 2; ++s) {
            const int ks = 2 * it + s;
            #pragma unroll
            for (int ni = 0; ni < 4; ++ni) {
                if (D0) r0[s * 4 + ni] = *(const bf16x8*)(b0f + (size_t)(((ni << 5) + ks) << 9));
                if (D1) r1[s * 4 + ni] = *(const bf16x8*)(b1f + (size_t)(((ni << 6) + ks) << 9));
            }
        }
    };
    auto mm = [&](int bo, bf16x8 (&r0)[8], bf16x8 (&r1)[8]) {
        const __bf16* Ap = AldsB + bo * (64 * LDSTR) + (wm * 16 + lj) * LDSTR + lq * 8;
        #pragma unroll
        for (int s = 0; s < 2; ++s) {
            bf16x8 af = *(const bf16x8*)(Ap + s * 32);
            #pragma unroll
            for (int ni = 0; ni < 4; ++ni) {
                if (D0) acc0[ni] = __builtin_amdgcn_mfma_f32_16x16x32_bf16(af, r0[s * 4 + ni], acc0[ni], 0, 0, 0);
                if (D1) acc1[ni] = __builtin_amdgcn_mfma_f32_16x16x32_bf16(af, r1[s * 4 + ni], acc1[ni], 0, 0, 0);
            }
        }
    };

    // prologue: A k0 -> buf0, prefetch A k64, B frags for it=0
    ra = *(const uint4*)(arw);
    *(uint4*)(AldsB + a_r * LDSTR + a_c) = ra;
    ra = *(const uint4*)(arw + 64);
    ldB(0, bc0, bc1);
    __syncthreads();

    for (int it = 0; it < 16; it += 2) {
        // even iteration: consume buf0 + bc
        if (it + 1 < 16) ldB(it + 1, bn0, bn1);
        mm(0, bc0, bc1);
        *(uint4*)(AldsB + (64 * LDSTR) + a_r * LDSTR + a_c) = ra;   // wr buf1
        if (it + 2 < 16) ra = *(const uint4*)(arw + (it + 2) * 64);
        __syncthreads();

        // odd iteration: consume buf1 + bn
        if (it + 2 < 16) ldB(it + 2, bc0, bc1);
        mm(1, bn0, bn1);
        if (it + 2 < 16) {
            *(uint4*)(AldsB + a_r * LDSTR + a_c) = ra;              // wr buf0
            if (it + 3 < 16) ra = *(const uint4*)(arw + (it + 3) * 64);
        }
        __syncthreads();
    }
}

// ---------------- persistent fused LSTM kernel ------------------------------
// 256 blocks, 1/CU, 512 threads. xcd owns gate-col slice [512x,512x+512);
// slot -> mt (0..7) x nb (0..3). Round r: L0(r) [r<128] + L1(r-1) [r>0];
// one flag inc per round; cnt[mt] target 32*r.

__global__ __launch_bounds__(512)
void lstm_persist(const float* __restrict__ x,
                  const __bf16* __restrict__ W0p, const __bf16* __restrict__ W1p,
                  const __bf16* __restrict__ Wfcp,
                  const float* __restrict__ Wi0p, const float* __restrict__ b1p,
                  const float* __restrict__ bfc,
                  __bf16* __restrict__ bufA, __bf16* __restrict__ bufB,
                  char* __restrict__ flagpage, float* __restrict__ out) {
    __shared__ __attribute__((aligned(16))) __bf16 Alds[2 * 64 * LDSTR];
    __shared__ float Aux1[128];
    __shared__ float Xlds[64 * 9];
    __shared__ float Wxlds[128 * 9];
    __shared__ int role[2];

    const int tid = threadIdx.x;

    // ---- claim XCD-local role ----
    if (tid == 0) {
        int xcd = __builtin_amdgcn_s_getreg(63508) & 7;   // HW_REG_XCC_ID
        int* xcnt = (int*)(flagpage + 1024) + xcd;
        int slot = __hip_atomic_fetch_add(xcnt, 1, __ATOMIC_RELAXED,
                                          __HIP_MEMORY_SCOPE_AGENT);
        role[0] = xcd; role[1] = slot;
    }
    __syncthreads();
    const int xcd = role[0];
    const int sl  = role[1];          // 0..31
    const int mt = sl >> 2, nb = sl & 3;
    const int m0 = mt * 64;
    const int n0 = xcd * 512 + nb * 128;
    int* cnt = (int*)(flagpage + (size_t)mt * 64);

    // one-time epilogue constants
    if (tid < 128) {
        Aux1[tid] = b1p[n0 + tid];
    } else if (tid < 256) {
        int nl = tid - 128;
        const float* sp = Wi0p + (n0 + nl) * 8;
        float* d = Wxlds + nl * 9;
        #pragma unroll
        for (int q = 0; q < 8; ++q) d[q] = sp[q];
    }

    const int l  = tid & 63, w = tid >> 6;
    const int wm = w & 3,   wn = w >> 2;
    const int lj = l & 15,  lq = l >> 4;
    const int jc = (n0 >> 2) + wn * 16 + lj;   // h column in [0,1024)

    // fragment-layout B base pointers (include tile base + lane elem offset)
    const int ntile = n0 >> 4;
    const __bf16* b0f = W0p + ((size_t)(ntile + wn * 4) << 14) + (l << 3);  // *32*512
    const __bf16* b1f = W1p + ((size_t)(ntile + wn * 4) << 15) + (l << 3);  // *64*512

    float c0[4], c1[4];
    #pragma unroll
    for (int r = 0; r < 4; ++r) { c0[r] = 0.f; c1[r] = 0.f; }

    f32x4 acc0[4], acc1[4];

    for (int r = 0; r <= 128; ++r) {
        const bool do0 = (r < 128), do1 = (r > 0);
        const __bf16* haPrev = bufA + (size_t)(r % 3) * HSZ;        // h_a(r-1)
        __bf16*       haOut  = bufA + (size_t)((r + 1) % 3) * HSZ;  // h_a(r)
        const __bf16* hbPrev = bufB + (size_t)((r + 2) % 3) * HSZ;  // h_b(r-2)
        __bf16*       hbOut  = bufB + (size_t)(r % 3) * HSZ;        // h_b(r-1)

        if (tid == 0) spin_ge(cnt, 32 * r);
        __syncthreads();
        inv_l1();

        // stage x_r (read-only input)
        if (do0 && tid < 64) {
            const float* xr = x + (m0 + tid) * 896 + r * 7;
            float* d = Xlds + tid * 9;
            #pragma unroll
            for (int q = 0; q < 7; ++q) d[q] = xr[q];
            d[7] = 1.0f;
        }

        #pragma unroll
        for (int j = 0; j < 4; ++j) {
            acc0[j] = (f32x4){0.f, 0.f, 0.f, 0.f};
            acc1[j] = (f32x4){0.f, 0.f, 0.f, 0.f};
        }

        const __bf16* abase = haPrev + m0 * 1024;
        if (do0 && do1)
            floopd<true, true >(abase, b0f, b1f, tid, Alds, acc0, acc1);
        else if (do0)
            floopd<true, false>(abase, b0f, b1f, tid, Alds, acc0, acc1);
        else
            floopd<false, true>(abase, b0f, b1f, tid, Alds, acc0, acc1);

        if (do1) {   // h_b(r-2) half of layer-1 GEMM (k in [1024,2048))
            floopd<false, true>(hbPrev + m0 * 1024, b0f, b1f + (32 << 9),
                                tid, Alds, acc0, acc1);
        }

        if (do0) {   // L0 epilogue: cell update + EA store h_a(r)
            #pragma unroll
            for (int rr = 0; rr < 4; ++rr) {
                int ml = wm * 16 + lq * 4 + rr;
                int m  = m0 + ml;
                float pre[4];
                #pragma unroll
                for (int g = 0; g < 4; ++g) pre[g] = acc0[g][rr];
                const float* xr = Xlds + ml * 9;
                #pragma unroll
                for (int g = 0; g < 4; ++g) {
                    const float* wx = Wxlds + (wn * 64 + g * 16 + lj) * 9;
                    float sv = 0.f;
                    #pragma unroll
                    for (int q = 0; q < 8; ++q) sv += xr[q] * wx[q];
                    pre[g] += sv;
                }
                float ig = sigm_f(pre[0]);
                float fg = sigm_f(pre[1]);
                float gv = tanh_f(pre[2]);
                float og = sigm_f(pre[3]);
                float cn = fg * c0[rr] + ig * gv;
                c0[rr] = cn;
                float hv = og * tanh_f(cn);
                unsigned u32 = __builtin_bit_cast(unsigned, hv);
                unsigned hu = (u32 + 0x7fffu + ((u32 >> 16) & 1u)) >> 16;
                int pv = __shfl_xor((int)hu, 1, 64);
                if ((lj & 1) == 0)
                    store_ea((unsigned*)(haOut + (size_t)m * 1024 + jc),
                             hu | ((unsigned)pv << 16));
            }
        }
        if (do1) {   // L1 epilogue: cell update + EA store h_b(r-1)
            #pragma unroll
            for (int rr = 0; rr < 4; ++rr) {
                int m = m0 + wm * 16 + lq * 4 + rr;
                float pre[4];
                #pragma unroll
                for (int g = 0; g < 4; ++g)
                    pre[g] = acc1[g][rr] + Aux1[wn * 64 + g * 16 + lj];
                float ig = sigm_f(pre[0]);
                float fg = sigm_f(pre[1]);
                float gv = tanh_f(pre[2]);
                float og = sigm_f(pre[3]);
                float cn = fg * c1[rr] + ig * gv;
                c1[rr] = cn;
                float hv = og * tanh_f(cn);
                unsigned u32 = __builtin_bit_cast(unsigned, hv);
                unsigned hu = (u32 + 0x7fffu + ((u32 >> 16) & 1u)) >> 16;
                int pv = __shfl_xor((int)hu, 1, 64);
                if ((lj & 1) == 0)
                    store_ea((unsigned*)(hbOut + (size_t)m * 1024 + jc),
                             hu | ((unsigned)pv << 16));
            }
        }
        __syncthreads();                 // vmcnt(0): EA stores performed
        if (tid == 0) signal_inc(cnt);
    }

    // ---- final FC: pred = h_b(127) @ Wfc^T + bfc  (nb==0, xcd<6) -----------
    if (nb == 0 && xcd < 6) {
        const int n0fc = xcd * 128;
        if (tid == 0) spin_ge(cnt, 32 * 129);
        __syncthreads();
        inv_l1();
        if (tid < 128) {
            int n = n0fc + tid;
            Aux1[tid] = (n < 672) ? bfc[n] : 0.f;
        }
        #pragma unroll
        for (int j = 0; j < 4; ++j)
            acc0[j] = (f32x4){0.f, 0.f, 0.f, 0.f};
        const __bf16* bfcf = Wfcp + ((size_t)(xcd * 8 + wn * 4) << 14) + (l << 3);
        // h_b(127) written in round 128 into bufB slot 128%3 = 2
        floopd<true, false>(bufB + (size_t)2 * HSZ + m0 * 1024,
                            bfcf, nullptr, tid, Alds, acc0, acc1);
        #pragma unroll
        for (int rr = 0; rr < 4; ++rr) {
            int m = m0 + wm * 16 + lq * 4 + rr;
            #pragma unroll
            for (int ni = 0; ni < 4; ++ni) {
                int n = n0fc + wn * 64 + ni * 16 + lj;
                if (n < 672)
                    out[m * 672 + n] = acc0[ni][rr] + Aux1[wn * 64 + ni * 16 + lj];
            }
        }
    }
}

// ---------------- workspace layout (bytes) ----------------------------------
#define O_W0P   0u            // 4096*1024*2  = 8388608
#define O_W1P   8388608u      // 4096*2048*2  = 16777216
#define O_WFCP  25165824u     // 768*1024*2   = 1572864
#define O_WI0P  26738688u     // 4096*8*4     = 131072
#define O_B1P   26869760u     // 4096*4       = 16384
#define O_FLG   26886144u     // 2048: cnt[8]@mt*64, xcnt@1024
#define O_BA    26888192u     // bufA[3] = 3*1048576  (slot0 zeroed = h_a(-1))
#define O_BB    30033920u     // bufB[3] = 3*1048576  (slot0 zeroed = h_b(-1))
#define WS_NEED 33179648u

extern "C" void kernel_launch(void* const* d_in, const int* in_sizes, int n_in,
                              void* d_out, int out_size, void* d_ws, size_t ws_size,
                              hipStream_t stream) {
    const float* x   = (const float*)d_in[0];
    const float* Wi0 = (const float*)d_in[1];
    const float* Wh0 = (const float*)d_in[2];
    const float* b0  = (const float*)d_in[3];
    const float* Wi1 = (const float*)d_in[4];
    const float* Wh1 = (const float*)d_in[5];
    const float* b1  = (const float*)d_in[6];
    const float* Wfc = (const float*)d_in[7];
    const float* bfc = (const float*)d_in[8];
    float* out = (float*)d_out;
    char*  ws  = (char*)d_ws;
    if (ws_size < WS_NEED) return;

    __bf16* W0p  = (__bf16*)(ws + O_W0P);
    __bf16* W1p  = (__bf16*)(ws + O_W1P);
    __bf16* Wfcp = (__bf16*)(ws + O_WFCP);
    float*  Wi0p = (float*)(ws + O_WI0P);
    float*  b1p  = (float*)(ws + O_B1P);
    char*   flg  = (char*)(ws + O_FLG);
    __bf16* bufA = (__bf16*)(ws + O_BA);
    __bf16* bufB = (__bf16*)(ws + O_BB);

    // zero flags + bufA slot0 (contiguous), and bufB slot0
    hipMemsetAsync(ws + O_FLG, 0, 2048u + 1048576u, stream);
    hipMemsetAsync(ws + O_BB, 0, 1048576u, stream);

    prep_w0   <<<2048, 256, 0, stream>>>(Wh0, W0p);
    prep_w1   <<<4096, 256, 0, stream>>>(Wi1, Wh1, W1p);
    prep_wfc  <<<384,  256, 0, stream>>>(Wfc, Wfcp);
    prep_small<<<16,   256, 0, stream>>>(Wi0, b0, b1, Wi0p, b1p);

    lstm_persist<<<256, 512, 0, stream>>>(x, W0p, W1p, Wfcp, Wi0p, b1p, bfc,
                                          bufA, bufB, flg, out);
}

// Round 2
// 6393.302 us; speedup vs baseline: 3.5094x; 3.5094x over previous
//
#include <hip/hip_runtime.h>
#include <hip/hip_bf16.h>

// ---------------------------------------------------------------------------
// LSTM_66675072303478: 2-layer LSTM (B=512,S=128,E=7,H=1024) + FC(1024->672)
//
// v13: zero-redundancy direct-B + A-only LDS.
//  - v12 post-mortem: 4 m-waves reading identical B fragments from global
//    amplified L2 capacity misses 9x (FETCH 2.7GB -> 25GB). Fix: wave grid
//    1(m) x 8(n) -- each wave owns a disjoint 16-col slice of BOTH gemms and
//    all 64 m rows, so every B byte is requested exactly once per block per
//    round (= v11's staged traffic, proven OK for L2).
//  - LDS carries only A (h tile): 8KB wr + 64KB rd per k-iter vs v11's 184KB
//    (v11 was LDS-bound: 1440cyc LDS vs 620cyc MFMA + 14k conflict-cyc/round).
//  - A LDS: unpadded [64][64] + 16B XOR swizzle (slot ^= row&7) -> conflict-
//    free reads (old +8-pad had 144B stride -> measured 4.7e8 conflicts).
//  - B loads global->VGPR, 2 frag-pairs/sub-iter, issued at top of sub-iter
//    so the barrier's vmcnt drain comes ~600cyc of MFMA later (latency hid).
//  - New gate permutation np=(j>>2)*16+g*4+(j&3): all 4 gates of a hidden
//    unit live in ONE 16-lane fragment; cell update combines them with
//    shfl_xor(4/8/12). Branchless act: one exp/lane, tanh-vs-sigm by algebra.
//  - Everything else proven in v9/v11: weights L2-resident per XCD, EA-point
//    h stores, 3-slot rotation + L1-only buffer_inv, one flag/round.
// ---------------------------------------------------------------------------

typedef __bf16 bf16x8 __attribute__((ext_vector_type(8)));
typedef float  f32x4  __attribute__((ext_vector_type(4)));

#define HSZ   (512 * 1024)  // one h buffer: 512 rows x 1024 cols (bf16)

__device__ __forceinline__ float tanh_f(float x) {
    x = fminf(30.f, fmaxf(-30.f, x));
    float e = __expf(-2.0f * x);
    return (1.0f - e) / (1.0f + e);
}

// np = (j>>2)*16 + g*4 + (j&3)  ->  original gate-major row g*1024 + j
__device__ __forceinline__ int perm_row(int np) {
    int g = (np >> 2) & 3;
    int j = ((np >> 4) << 2) | (np & 3);
    return g * 1024 + j;
}

// ---- relaxed-only flag ops (NO acquire/release -> no L2 inv/wb) ------------
__device__ __forceinline__ void spin_ge(const int* p, int target) {
    while (__hip_atomic_load(p, __ATOMIC_RELAXED, __HIP_MEMORY_SCOPE_AGENT) < target)
        __builtin_amdgcn_s_sleep(1);
}
__device__ __forceinline__ void signal_inc(int* p) {
    __hip_atomic_fetch_add(p, 1, __ATOMIC_RELAXED, __HIP_MEMORY_SCOPE_AGENT);
}
// L1-only invalidate (CU scope). Leaves L2/MALL intact; compiler fence.
__device__ __forceinline__ void inv_l1() {
    asm volatile("buffer_inv" ::: "memory");
}
// EA-point coherent dword store: bypasses L2s -> visible chip-wide.
__device__ __forceinline__ void store_ea(unsigned* p, unsigned v) {
    __hip_atomic_store(p, v, __ATOMIC_RELAXED, __HIP_MEMORY_SCOPE_AGENT);
}

// ---------------- weight prep kernels (run every call) ----------------------
// Fragment layout (validated by v12 PASS): for permuted col np, k:
//   tile t = np>>4, slice ks = k>>5,
//   lane = (np&15) + ((k>>3)&3)*16, elem = lane*8 + (k&7)
// -> one wave B-frag load = 64 lanes x 16B contiguous = 1KB coalesced.

__global__ void prep_w0(const float* __restrict__ Wh0, __bf16* __restrict__ W0f) {
    int idx = blockIdx.x * 256 + threadIdx.x;       // 4096 np x 128 k-chunks
    int np = idx >> 7, c = idx & 127;
    int k = c << 3;
    int r = perm_row(np);
    const float* s = Wh0 + r * 1024 + k;
    float4 v0 = *(const float4*)s;
    float4 v1 = *(const float4*)(s + 4);
    int t = np >> 4, ks = k >> 5;
    int lane = (np & 15) + ((c & 3) << 4);
    __bf16* o = W0f + ((size_t)(t * 32 + ks) << 9) + (lane << 3);
    o[0] = (__bf16)v0.x; o[1] = (__bf16)v0.y; o[2] = (__bf16)v0.z; o[3] = (__bf16)v0.w;
    o[4] = (__bf16)v1.x; o[5] = (__bf16)v1.y; o[6] = (__bf16)v1.z; o[7] = (__bf16)v1.w;
}

__global__ void prep_w1(const float* __restrict__ Wi1, const float* __restrict__ Wh1,
                        __bf16* __restrict__ W1f) {
    int idx = blockIdx.x * 256 + threadIdx.x;       // 4096 np x 256 k-chunks
    int np = idx >> 8, c = idx & 255;
    int k = c << 3;
    int r = perm_row(np);
    const float* s = (k < 1024) ? (Wi1 + r * 1024 + k) : (Wh1 + r * 1024 + (k - 1024));
    float4 v0 = *(const float4*)s;
    float4 v1 = *(const float4*)(s + 4);
    int t = np >> 4, ks = k >> 5;                   // ks in [0,64)
    int lane = (np & 15) + ((c & 3) << 4);
    __bf16* o = W1f + ((size_t)(t * 64 + ks) << 9) + (lane << 3);
    o[0] = (__bf16)v0.x; o[1] = (__bf16)v0.y; o[2] = (__bf16)v0.z; o[3] = (__bf16)v0.w;
    o[4] = (__bf16)v1.x; o[5] = (__bf16)v1.y; o[6] = (__bf16)v1.z; o[7] = (__bf16)v1.w;
}

__global__ void prep_wfc(const float* __restrict__ Wfc, __bf16* __restrict__ Wfcf) {
    int idx = blockIdx.x * 256 + threadIdx.x;       // 768 n x 128 k-chunks
    int n = idx >> 7, c = idx & 127;
    int k = c << 3;
    int t = n >> 4, ks = k >> 5;
    int lane = (n & 15) + ((c & 3) << 4);
    __bf16* o = Wfcf + ((size_t)(t * 32 + ks) << 9) + (lane << 3);
    if (n < 672) {
        const float* s = Wfc + n * 1024 + k;
        float4 v0 = *(const float4*)s;
        float4 v1 = *(const float4*)(s + 4);
        o[0] = (__bf16)v0.x; o[1] = (__bf16)v0.y; o[2] = (__bf16)v0.z; o[3] = (__bf16)v0.w;
        o[4] = (__bf16)v1.x; o[5] = (__bf16)v1.y; o[6] = (__bf16)v1.z; o[7] = (__bf16)v1.w;
    } else {
        #pragma unroll
        for (int q = 0; q < 8; ++q) o[q] = (__bf16)0.f;
    }
}

__global__ void prep_small(const float* __restrict__ Wi0, const float* __restrict__ b0,
                           const float* __restrict__ b1,
                           float* __restrict__ Wi0p, float* __restrict__ b1p) {
    int np = blockIdx.x * 256 + threadIdx.x;
    int r = perm_row(np);
    float* o = Wi0p + np * 8;
    #pragma unroll
    for (int q = 0; q < 7; ++q) o[q] = Wi0[r * 7 + q];
    o[7] = b0[r];
    b1p[np] = b1[r];
}

// ---------------- fused K=1024 sub-loop: A via swizzled LDS, B direct -------
// 8 n-waves, wave tile 64(m) x 16(n). Per sub-iter (k64): 8 ds_read_b128 (A),
// 16 MFMA, 4 global B-frag loads (issued first), 1 A global ld + 1 ds_write.
// A LDS [2][64][64] bf16, 16B-slot XOR swizzle: slot' = slot ^ (row&7).

template <bool D0, bool D1>
__device__ __forceinline__ void floopd(const __bf16* __restrict__ abase,
                                       const __bf16* __restrict__ b0f,
                                       const __bf16* __restrict__ b1f,
                                       int tid, __bf16* AldsB,
                                       f32x4 (&acc0)[4], f32x4 (&acc1)[4]) {
    const int a_r = tid >> 3;             // 0..63 row
    const int sl8 = tid & 7;              // 16B slot within 128B row
    const int l  = tid & 63;
    const int lj = l & 15, lq = l >> 4;
    const int r7 = lj & 7;

    const __bf16* arw = abase + a_r * 1024 + sl8 * 8;
    const int woff = a_r * 64 + ((sl8 ^ (a_r & 7)) << 3);   // swizzled write

    bf16x8 P0[2], P1[2], Q0[2], Q1[2];
    uint4 rA0, rA1;

    auto ldB = [&](int it, bf16x8 (&r0)[2], bf16x8 (&r1)[2]) {
        #pragma unroll
        for (int s = 0; s < 2; ++s) {
            const int ks = 2 * it + s;
            if (D0) r0[s] = *(const bf16x8*)(b0f + ((size_t)ks << 9));
            if (D1) r1[s] = *(const bf16x8*)(b1f + ((size_t)ks << 9));
        }
    };
    auto mm = [&](int bo, bf16x8 (&r0)[2], bf16x8 (&r1)[2]) {
        const __bf16* Ab = AldsB + bo * 4096;
        #pragma unroll
        for (int s = 0; s < 2; ++s) {
            #pragma unroll
            for (int mi = 0; mi < 4; ++mi) {
                bf16x8 af = *(const bf16x8*)(Ab + (mi * 16 + lj) * 64 +
                                             ((((s << 2) | lq) ^ r7) << 3));
                if (D0) acc0[mi] = __builtin_amdgcn_mfma_f32_16x16x32_bf16(af, r0[s], acc0[mi], 0, 0, 0);
                if (D1) acc1[mi] = __builtin_amdgcn_mfma_f32_16x16x32_bf16(af, r1[s], acc1[mi], 0, 0, 0);
            }
        }
    };

    // prologue: A(0) -> buf0, A(1) -> rA1, B(0) -> P
    {
        uint4 t0 = *(const uint4*)(arw);
        *(uint4*)(AldsB + woff) = t0;
    }
    rA1 = *(const uint4*)(arw + 64);
    ldB(0, P0, P1);
    __syncthreads();

    for (int i2 = 0; i2 < 8; ++i2) {
        const int it = i2 * 2;
        // even sub-iter: consume buf0 + P(it); prefetch issued FIRST
        ldB(it + 1, Q0, Q1);
        if (it + 2 < 16) rA0 = *(const uint4*)(arw + (it + 2) * 64);
        mm(0, P0, P1);
        *(uint4*)(AldsB + 4096 + woff) = rA1;            // A(it+1) -> buf1
        __syncthreads();
        // odd sub-iter: consume buf1 + Q(it+1)
        if (it + 2 < 16) ldB(it + 2, P0, P1);
        if (it + 3 < 16) rA1 = *(const uint4*)(arw + (it + 3) * 64);
        mm(1, Q0, Q1);
        if (it + 2 < 16) *(uint4*)(AldsB + woff) = rA0;  // A(it+2) -> buf0
        __syncthreads();
    }
}

// ---------------- persistent fused LSTM kernel ------------------------------
// 256 blocks, 1/CU, 512 threads. xcd owns gate-col slice [512x,512x+512);
// slot -> mt (0..7) x nb (0..3). Round r: L0(r) [r<128] + L1(r-1) [r>0];
// one flag inc per round; cnt[mt] target 32*r.

__global__ __launch_bounds__(512)
void lstm_persist(const float* __restrict__ x,
                  const __bf16* __restrict__ W0p, const __bf16* __restrict__ W1p,
                  const __bf16* __restrict__ Wfcp,
                  const float* __restrict__ Wi0p, const float* __restrict__ b1p,
                  const float* __restrict__ bfc,
                  __bf16* __restrict__ bufA, __bf16* __restrict__ bufB,
                  char* __restrict__ flagpage, float* __restrict__ out) {
    __shared__ __attribute__((aligned(16))) __bf16 Alds[2 * 64 * 64];
    __shared__ float Aux1[128];
    __shared__ float Xlds[64 * 9];
    __shared__ float Wxlds[128 * 9];
    __shared__ int role[2];

    const int tid = threadIdx.x;

    // ---- claim XCD-local role ----
    if (tid == 0) {
        int xcd = __builtin_amdgcn_s_getreg(63508) & 7;   // HW_REG_XCC_ID
        int* xcnt = (int*)(flagpage + 1024) + xcd;
        int slot = __hip_atomic_fetch_add(xcnt, 1, __ATOMIC_RELAXED,
                                          __HIP_MEMORY_SCOPE_AGENT);
        role[0] = xcd; role[1] = slot;
    }
    __syncthreads();
    const int xcd = role[0];
    const int sl  = role[1];          // 0..31
    const int mt = sl >> 2, nb = sl & 3;
    const int m0 = mt * 64;
    const int n0 = xcd * 512 + nb * 128;
    int* cnt = (int*)(flagpage + (size_t)mt * 64);

    // one-time epilogue constants
    if (tid < 128) {
        Aux1[tid] = b1p[n0 + tid];
    } else if (tid < 256) {
        int nl = tid - 128;
        const float* sp = Wi0p + (n0 + nl) * 8;
        float* d = Wxlds + nl * 9;
        #pragma unroll
        for (int q = 0; q < 8; ++q) d[q] = sp[q];
    }

    const int l  = tid & 63, w = tid >> 6;   // wave w = n-slice owner
    const int lj = l & 15,  lq = l >> 4;
    const int jc = (n0 >> 2) + (w << 2);     // hidden-col base of this wave

    // per-wave fragment base pointers (tile base + lane elem offset)
    const int t = (n0 >> 4) + w;
    const __bf16* b0f = W0p + ((size_t)t << 14) + (l << 3);  // 32 slices/tile
    const __bf16* b1f = W1p + ((size_t)t << 15) + (l << 3);  // 64 slices/tile

    // lane gate id: np&15 = g*4 + u
    const float g2 = (((l >> 2) & 3) == 2) ? 1.f : 0.f;
    const float sc = 1.f + g2;
    const float* wx = Wxlds + (w * 16 + lj) * 9;

    float c0[16], c1[16];
    #pragma unroll
    for (int q = 0; q < 16; ++q) { c0[q] = 0.f; c1[q] = 0.f; }

    f32x4 acc0[4], acc1[4];

    for (int r = 0; r <= 128; ++r) {
        const bool do0 = (r < 128), do1 = (r > 0);
        const __bf16* haPrev = bufA + (size_t)(r % 3) * HSZ;        // h_a(r-1)
        __bf16*       haOut  = bufA + (size_t)((r + 1) % 3) * HSZ;  // h_a(r)
        const __bf16* hbPrev = bufB + (size_t)((r + 2) % 3) * HSZ;  // h_b(r-2)
        __bf16*       hbOut  = bufB + (size_t)(r % 3) * HSZ;        // h_b(r-1)

        if (tid == 0) spin_ge(cnt, 32 * r);
        __syncthreads();
        inv_l1();

        // stage x_r (read-only input)
        if (do0 && tid < 64) {
            const float* xr = x + (m0 + tid) * 896 + r * 7;
            float* d = Xlds + tid * 9;
            #pragma unroll
            for (int q = 0; q < 7; ++q) d[q] = xr[q];
            d[7] = 1.0f;
        }

        #pragma unroll
        for (int j = 0; j < 4; ++j) {
            acc0[j] = (f32x4){0.f, 0.f, 0.f, 0.f};
            acc1[j] = (f32x4){0.f, 0.f, 0.f, 0.f};
        }

        const __bf16* abase = haPrev + m0 * 1024;
        if (do0 && do1)
            floopd<true, true >(abase, b0f, b1f, tid, Alds, acc0, acc1);
        else if (do0)
            floopd<true, false>(abase, b0f, b1f, tid, Alds, acc0, acc1);
        else
            floopd<false, true>(abase, b0f, b1f, tid, Alds, acc0, acc1);

        if (do1) {   // h_b(r-2) half of layer-1 GEMM (k in [1024,2048))
            floopd<false, true>(hbPrev + m0 * 1024, b0f, b1f + (32 << 9),
                                tid, Alds, acc0, acc1);
        }

        if (do0) {   // L0 epilogue: gates in-lane -> shfl combine -> EA store
            #pragma unroll
            for (int mi = 0; mi < 4; ++mi) {
                #pragma unroll
                for (int rr = 0; rr < 4; ++rr) {
                    int row = mi * 16 + lq * 4 + rr;
                    int m = m0 + row;
                    float pre = acc0[mi][rr];
                    const float* xr = Xlds + row * 9;
                    #pragma unroll
                    for (int q = 0; q < 8; ++q) pre += xr[q] * wx[q];
                    float px = fminf(30.f, fmaxf(-30.f, pre * sc));
                    float e = __expf(-px);
                    float a = (1.f - g2 * e) / (1.f + e);   // sigm / tanh
                    float t4  = __shfl_xor(a, 4, 64);       // f
                    float t8  = __shfl_xor(a, 8, 64);       // g
                    float t12 = __shfl_xor(a, 12, 64);      // o
                    float cn = t4 * c0[mi * 4 + rr] + a * t8;
                    c0[mi * 4 + rr] = cn;
                    float hv = t12 * tanh_f(cn);
                    unsigned u32 = __builtin_bit_cast(unsigned, hv);
                    unsigned hu = (u32 + 0x7fffu + ((u32 >> 16) & 1u)) >> 16;
                    int pv = __shfl_xor((int)hu, 1, 64);
                    if ((lj < 4) && ((l & 1) == 0))
                        store_ea((unsigned*)(haOut + (size_t)m * 1024 + jc + lj),
                                 hu | ((unsigned)pv << 16));
                }
            }
        }
        if (do1) {   // L1 epilogue
            const float b1v = Aux1[w * 16 + lj];
            #pragma unroll
            for (int mi = 0; mi < 4; ++mi) {
                #pragma unroll
                for (int rr = 0; rr < 4; ++rr) {
                    int m = m0 + mi * 16 + lq * 4 + rr;
                    float pre = acc1[mi][rr] + b1v;
                    float px = fminf(30.f, fmaxf(-30.f, pre * sc));
                    float e = __expf(-px);
                    float a = (1.f - g2 * e) / (1.f + e);
                    float t4  = __shfl_xor(a, 4, 64);
                    float t8  = __shfl_xor(a, 8, 64);
                    float t12 = __shfl_xor(a, 12, 64);
                    float cn = t4 * c1[mi * 4 + rr] + a * t8;
                    c1[mi * 4 + rr] = cn;
                    float hv = t12 * tanh_f(cn);
                    unsigned u32 = __builtin_bit_cast(unsigned, hv);
                    unsigned hu = (u32 + 0x7fffu + ((u32 >> 16) & 1u)) >> 16;
                    int pv = __shfl_xor((int)hu, 1, 64);
                    if ((lj < 4) && ((l & 1) == 0))
                        store_ea((unsigned*)(hbOut + (size_t)m * 1024 + jc + lj),
                                 hu | ((unsigned)pv << 16));
                }
            }
        }
        __syncthreads();                 // vmcnt(0): EA stores performed
        if (tid == 0) signal_inc(cnt);
    }

    // ---- final FC: pred = h_b(127) @ Wfc^T + bfc  (nb==0, xcd<6) -----------
    if (nb == 0 && xcd < 6) {
        const int n0fc = xcd * 128;
        if (tid == 0) spin_ge(cnt, 32 * 129);
        __syncthreads();
        inv_l1();
        if (tid < 128) {
            int n = n0fc + tid;
            Aux1[tid] = (n < 672) ? bfc[n] : 0.f;
        }
        __syncthreads();
        #pragma unroll
        for (int j = 0; j < 4; ++j)
            acc0[j] = (f32x4){0.f, 0.f, 0.f, 0.f};
        const __bf16* bfcf = Wfcp + ((size_t)(xcd * 8 + w) << 14) + (l << 3);
        // h_b(127) written in round 128 into bufB slot 128%3 = 2
        floopd<true, false>(bufB + (size_t)2 * HSZ + m0 * 1024,
                            bfcf, nullptr, tid, Alds, acc0, acc1);
        const int n = n0fc + w * 16 + lj;
        if (n < 672) {
            const float bv = Aux1[w * 16 + lj];
            #pragma unroll
            for (int mi = 0; mi < 4; ++mi) {
                #pragma unroll
                for (int rr = 0; rr < 4; ++rr) {
                    int m = m0 + mi * 16 + lq * 4 + rr;
                    out[m * 672 + n] = acc0[mi][rr] + bv;
                }
            }
        }
    }
}

// ---------------- workspace layout (bytes) ----------------------------------
#define O_W0P   0u            // 4096*1024*2  = 8388608
#define O_W1P   8388608u      // 4096*2048*2  = 16777216
#define O_WFCP  25165824u     // 768*1024*2   = 1572864
#define O_WI0P  26738688u     // 4096*8*4     = 131072
#define O_B1P   26869760u     // 4096*4       = 16384
#define O_FLG   26886144u     // 2048: cnt[8]@mt*64, xcnt@1024
#define O_BA    26888192u     // bufA[3] = 3*1048576  (slot0 zeroed = h_a(-1))
#define O_BB    30033920u     // bufB[3] = 3*1048576  (slot0 zeroed = h_b(-1))
#define WS_NEED 33179648u

extern "C" void kernel_launch(void* const* d_in, const int* in_sizes, int n_in,
                              void* d_out, int out_size, void* d_ws, size_t ws_size,
                              hipStream_t stream) {
    const float* x   = (const float*)d_in[0];
    const float* Wi0 = (const float*)d_in[1];
    const float* Wh0 = (const float*)d_in[2];
    const float* b0  = (const float*)d_in[3];
    const float* Wi1 = (const float*)d_in[4];
    const float* Wh1 = (const float*)d_in[5];
    const float* b1  = (const float*)d_in[6];
    const float* Wfc = (const float*)d_in[7];
    const float* bfc = (const float*)d_in[8];
    float* out = (float*)d_out;
    char*  ws  = (char*)d_ws;
    if (ws_size < WS_NEED) return;

    __bf16* W0p  = (__bf16*)(ws + O_W0P);
    __bf16* W1p  = (__bf16*)(ws + O_W1P);
    __bf16* Wfcp = (__bf16*)(ws + O_WFCP);
    float*  Wi0p = (float*)(ws + O_WI0P);
    float*  b1p  = (float*)(ws + O_B1P);
    char*   flg  = (char*)(ws + O_FLG);
    __bf16* bufA = (__bf16*)(ws + O_BA);
    __bf16* bufB = (__bf16*)(ws + O_BB);

    // zero flags + bufA slot0 (contiguous), and bufB slot0
    hipMemsetAsync(ws + O_FLG, 0, 2048u + 1048576u, stream);
    hipMemsetAsync(ws + O_BB, 0, 1048576u, stream);

    prep_w0   <<<2048, 256, 0, stream>>>(Wh0, W0p);
    prep_w1   <<<4096, 256, 0, stream>>>(Wi1, Wh1, W1p);
    prep_wfc  <<<384,  256, 0, stream>>>(Wfc, Wfcp);
    prep_small<<<16,   256, 0, stream>>>(Wi0, b0, b1, Wi0p, b1p);

    lstm_persist<<<256, 512, 0, stream>>>(x, W0p, W1p, Wfcp, Wi0p, b1p, bfc,
                                          bufA, bufB, flg, out);
}